// Round 2
// baseline (2998.026 us; speedup 1.0000x reference)
//
#include <hip/hip_runtime.h>
#include <cstdint>
#include <cstddef>

// Problem constants: B=4, L=2048, D=512
// M = B*L = 8192
// Stage 1: qkv GEMM  M=8192, K=3072, N=2048 (only chunks {0,2,4,5} of W_qkv rows)
// Stage 2: per batch, scores = Q @ K^T (2048x2048, K=512)
// Stage 3: masked softmax rows (pad_mask as int32 — harness widens jnp.bool_)
// Stage 4: per batch, AO = P @ [Vr|Vi]  (2048x1024, K=2048)
// Stage 5: out = AO @ W_out^T + b_out (8192x1024, K=1024), split-stored.

#define TM 128
#define TN 128
#define TK 16
#define PAD 4

struct GArgs {
  const float* A; int lda;   // row-major M x K (plain-A modes)
  const float* B; int ldb;   // NT: N x K row-major; NN (mode 2): K x N row-major
  float* C; int ldc;
  int K;
  const float* bias;         // nullable
  const float* x0; const float* x1; const float* x2;
  const float* x3; const float* x4; const float* x5;   // mode 0 virtual concat A
  float* C2;                 // mode 3: base for cols >= 512
};

// MODE 0: qkv  (virtual-concat A, NT B with W-row remap, bias, plain C)
// MODE 1: scores (plain NT, no bias)
// MODE 2: pv   (plain A, NN B, no bias)
// MODE 3: out  (plain NT, bias, split store)
template<int MODE>
__launch_bounds__(256)
__global__ void gemm_kern(GArgs g) {
  __shared__ float As[TK][TM + PAD];
  __shared__ float Bs[TK][TN + PAD];
  const int tid = threadIdx.x;
  const int m0 = blockIdx.y * TM;
  const int n0 = blockIdx.x * TN;

  // W_qkv row-chunk remap for mode 0: output col chunks {q_r,k_r,v_r,v_i} -> W rows {0,2,4,5}*512
  size_t brow0;
  if (MODE == 0) {
    int c = n0 >> 9;
    int m = (c == 0) ? 0 : (c == 1) ? 2 : (c == 2) ? 4 : 5;
    brow0 = (size_t)(m * 512 + (n0 & 511));
  } else {
    brow0 = (size_t)n0;
  }

  float acc[8][8];
#pragma unroll
  for (int i = 0; i < 8; ++i)
#pragma unroll
    for (int j = 0; j < 8; ++j) acc[i][j] = 0.f;

  const int tx = tid & 15, ty = tid >> 4;

  for (int k0 = 0; k0 < g.K; k0 += TK) {
    // ---- A tile -> As[k][m] (transposed store)
#pragma unroll
    for (int it = 0; it < 2; ++it) {
      int f = tid + it * 256;       // float4 id, 0..511
      int r = f >> 2;               // row in tile (0..127)
      int kq = (f & 3) << 2;        // k offset in tile (0,4,8,12)
      const float* ap;
      if (MODE == 0) {
        int part = k0 >> 9;         // 0..5, uniform across the tile (512 % 16 == 0)
        const float* xb;
        switch (part) {
          case 0: xb = g.x0; break;
          case 1: xb = g.x1; break;
          case 2: xb = g.x2; break;
          case 3: xb = g.x3; break;
          case 4: xb = g.x4; break;
          default: xb = g.x5; break;
        }
        ap = xb + (size_t)(m0 + r) * 512 + ((k0 & 511) + kq);
      } else {
        ap = g.A + (size_t)(m0 + r) * g.lda + (k0 + kq);
      }
      float4 v = *(const float4*)ap;
      As[kq + 0][r] = v.x; As[kq + 1][r] = v.y;
      As[kq + 2][r] = v.z; As[kq + 3][r] = v.w;
    }
    // ---- B tile -> Bs[k][n]
    if (MODE == 2) {  // NN: B[k][n]
#pragma unroll
      for (int it = 0; it < 2; ++it) {
        int f = tid + it * 256;
        int kk = f >> 5;            // 0..15
        int c4 = (f & 31) << 2;     // 0..124
        float4 v = *(const float4*)(g.B + (size_t)(k0 + kk) * g.ldb + (n0 + c4));
        *(float4*)&Bs[kk][c4] = v;
      }
    } else {          // NT: B[n][k]
#pragma unroll
      for (int it = 0; it < 2; ++it) {
        int f = tid + it * 256;
        int r = f >> 2;
        int kq = (f & 3) << 2;
        float4 v = *(const float4*)(g.B + (brow0 + r) * g.ldb + (k0 + kq));
        Bs[kq + 0][r] = v.x; Bs[kq + 1][r] = v.y;
        Bs[kq + 2][r] = v.z; Bs[kq + 3][r] = v.w;
      }
    }
    __syncthreads();
    // ---- compute
#pragma unroll
    for (int kk = 0; kk < TK; ++kk) {
      float a[8], b[8];
      *(float4*)&a[0] = *(const float4*)&As[kk][ty * 4];
      *(float4*)&a[4] = *(const float4*)&As[kk][ty * 4 + 64];
      *(float4*)&b[0] = *(const float4*)&Bs[kk][tx * 4];
      *(float4*)&b[4] = *(const float4*)&Bs[kk][tx * 4 + 64];
#pragma unroll
      for (int i = 0; i < 8; ++i)
#pragma unroll
        for (int j = 0; j < 8; ++j) acc[i][j] += a[i] * b[j];
    }
    __syncthreads();
  }

  // ---- epilogue
  const float* bptr = nullptr;
  if ((MODE == 0 || MODE == 3) && g.bias)
    bptr = (MODE == 0) ? (g.bias + brow0 - (size_t)n0) : g.bias;

#pragma unroll
  for (int i = 0; i < 8; ++i) {
    int m = m0 + ty * 4 + (i & 3) + ((i >> 2) * 64);
#pragma unroll
    for (int jh = 0; jh < 2; ++jh) {
      int n = n0 + tx * 4 + jh * 64;
      float4 v;
      v.x = acc[i][jh * 4 + 0];
      v.y = acc[i][jh * 4 + 1];
      v.z = acc[i][jh * 4 + 2];
      v.w = acc[i][jh * 4 + 3];
      if ((MODE == 0 || MODE == 3) && bptr) {
        v.x += bptr[n]; v.y += bptr[n + 1]; v.z += bptr[n + 2]; v.w += bptr[n + 3];
      }
      float* cp;
      if (MODE == 3) {
        cp = (n0 < 512) ? (g.C + (size_t)m * g.ldc + n)
                        : (g.C2 + (size_t)m * g.ldc + (n - 512));
      } else {
        cp = g.C + (size_t)m * g.ldc + n;
      }
      *(float4*)cp = v;
    }
  }
}

// One wave per row; 4 rows per block. S (2048 wide) scaled+masked+softmaxed in place.
// mask: int32 (harness widens jnp.bool_ to int)
__launch_bounds__(256)
__global__ void softmax_rows(float* S, const int* mask) {
  const int lane = threadIdx.x & 63;
  const int wave = threadIdx.x >> 6;
  const int row = blockIdx.x * 4 + wave;
  float* s = S + (size_t)row * 2048;
  const float scale = 0.04419417382415922f;  // 512^-0.5

  float mx = -INFINITY;
  for (int k = lane; k < 2048; k += 64) {
    float v = mask[k] ? -INFINITY : s[k] * scale;
    mx = fmaxf(mx, v);
  }
#pragma unroll
  for (int off = 32; off; off >>= 1) mx = fmaxf(mx, __shfl_xor(mx, off));

  float sum = 0.f;
  for (int k = lane; k < 2048; k += 64) {
    float e = mask[k] ? 0.f : __expf(s[k] * scale - mx);
    s[k] = e;
    sum += e;
  }
#pragma unroll
  for (int off = 32; off; off >>= 1) sum += __shfl_xor(sum, off);

  float r = 1.f / sum;
  for (int k = lane; k < 2048; k += 64) s[k] *= r;
}

extern "C" void kernel_launch(void* const* d_in, const int* in_sizes, int n_in,
                              void* d_out, int out_size, void* d_ws, size_t ws_size,
                              hipStream_t stream) {
  const float* qr = (const float*)d_in[0];
  const float* qi = (const float*)d_in[1];
  const float* kr = (const float*)d_in[2];
  const float* ki = (const float*)d_in[3];
  const float* vr = (const float*)d_in[4];
  const float* vi = (const float*)d_in[5];
  const int* pm = (const int*)d_in[6];  // jnp.bool_ -> int32 per harness "integer -> const int*"
  const float* Wqkv = (const float*)d_in[7];
  const float* bqkv = (const float*)d_in[8];
  const float* Wout = (const float*)d_in[9];
  const float* bout = (const float*)d_in[10];
  float* out = (float*)d_out;

  // ws layout (floats): QKVV 8192x2048 | AO 8192x1024 | S 2048x2048  => ~117 MB
  float* QKVV = (float*)d_ws;
  float* AO = QKVV + (size_t)8192 * 2048;
  float* S = AO + (size_t)8192 * 1024;

  dim3 blk(256);

  // Stage 1: qkv GEMM (only needed chunks), cols: [Q | K | Vr | Vi] each 512
  {
    GArgs a{};
    a.B = Wqkv; a.ldb = 3072;
    a.C = QKVV; a.ldc = 2048;
    a.K = 3072;
    a.bias = bqkv;
    a.x0 = qr; a.x1 = qi; a.x2 = kr; a.x3 = ki; a.x4 = vr; a.x5 = vi;
    gemm_kern<0><<<dim3(2048 / TN, 8192 / TM), blk, 0, stream>>>(a);
  }

  // Stages 2-4 per batch (S buffer reused sequentially)
  for (int b = 0; b < 4; ++b) {
    const float* base = QKVV + (size_t)b * 2048 * 2048;
    {
      GArgs sc{};
      sc.A = base; sc.lda = 2048;          // Q: cols [0,512)
      sc.B = base + 512; sc.ldb = 2048;    // K: cols [512,1024), NT
      sc.C = S; sc.ldc = 2048;
      sc.K = 512;
      gemm_kern<1><<<dim3(2048 / TN, 2048 / TM), blk, 0, stream>>>(sc);
    }
    softmax_rows<<<512, 256, 0, stream>>>(S, pm + (size_t)b * 2048);
    {
      GArgs pv{};
      pv.A = S; pv.lda = 2048;
      pv.B = base + 1024; pv.ldb = 2048;   // [Vr|Vi]: cols [1024,2048), NN
      pv.C = AO + (size_t)b * 2048 * 1024; pv.ldc = 1024;
      pv.K = 2048;
      gemm_kern<2><<<dim3(1024 / TN, 2048 / TM), blk, 0, stream>>>(pv);
    }
  }

  // Stage 5: out projection + split store
  {
    GArgs o{};
    o.A = AO; o.lda = 1024;
    o.B = Wout; o.ldb = 1024;
    o.C = out; o.ldc = 512;
    o.C2 = out + (size_t)8192 * 512;
    o.K = 1024;
    o.bias = bout;
    gemm_kern<3><<<dim3(1024 / TN, 8192 / TM), blk, 0, stream>>>(o);
  }
}

// Round 3
// 517.654 us; speedup vs baseline: 5.7916x; 5.7916x over previous
//
#include <hip/hip_runtime.h>
#include <cstdint>
#include <cstddef>

typedef unsigned short ushort;
typedef __attribute__((ext_vector_type(8))) short short8;   // 8 x bf16 (4 VGPRs)
typedef __attribute__((ext_vector_type(4))) float f32x4;

__device__ __forceinline__ float bf2f(ushort u) {
  union { unsigned u; float f; } c; c.u = ((unsigned)u) << 16; return c.f;
}
__device__ __forceinline__ ushort f2bf(float f) {
  union { float f; unsigned u; } c; c.f = f;
  unsigned u = c.u;
  return (ushort)((u + 0x7fffu + ((u >> 16) & 1u)) >> 16);   // RNE
}

#define G2L(g, l) __builtin_amdgcn_global_load_lds( \
    (const __attribute__((address_space(1))) void*)(g), \
    (__attribute__((address_space(3))) void*)(l), 16, 0, 0)

// ---------------- MFMA GEMM: C[M,N] = A[M,K] . B[N,K]^T (+bias) ----------------
// 128x128 tile, BK=32, 4 waves, each wave 64x64 via 4x4 MFMA 16x16x32 tiles.
// MODE 0: stage1 qkv  (bias4 fp32, write bf16)
// MODE 1: stage2 scores (no bias, write bf16)
// MODE 2: stage4 PV     (no bias, write bf16)
// MODE 3: stage5 out    (bias fp32, write fp32 split at col 512)
struct MArgs {
  const ushort* A; int lda; long asz;
  const ushort* B; int ldb; long bsz;
  void* C; int ldc; long csz;
  int K;
  const float* bias;
  float* C2;
};

template<int MODE>
__launch_bounds__(256)
__global__ void mfma_gemm(MArgs g) {
  __shared__ ushort As[128 * 32];
  __shared__ ushort Bs[128 * 32];
  const int tid = threadIdx.x;
  const int lane = tid & 63;
  const int wave = tid >> 6;
  const int z = blockIdx.z;
  const long m0 = (long)blockIdx.y * 128;
  const long n0 = (long)blockIdx.x * 128;
  const ushort* A = g.A + (long)z * g.asz;
  const ushort* B = g.B + (long)z * g.bsz;

  // ---- staging addresses (fixed per lane; swizzle: lds chunk c' holds global chunk (c'-row>>1)&3)
  const int srow = lane >> 2;                                  // row within 16-row block
  const int skq = (((lane & 3) - ((lane >> 3) & 3)) & 3) * 8;  // swizzled global k-offset (elems)
  const ushort* ga0 = A + (m0 + wave * 16 + srow) * g.lda + skq;
  const ushort* ga1 = A + (m0 + (wave + 4) * 16 + srow) * g.lda + skq;
  const ushort* gb0 = B + (n0 + wave * 16 + srow) * g.ldb + skq;
  const ushort* gb1 = B + (n0 + (wave + 4) * 16 + srow) * g.ldb + skq;
  ushort* lA0 = As + tid * 8;
  ushort* lA1 = As + 2048 + tid * 8;
  ushort* lB0 = Bs + tid * 8;
  ushort* lB1 = Bs + 2048 + tid * 8;

  // ---- fragment read addresses (fixed per lane)
  const int wm = (wave >> 1) * 64;
  const int wn = (wave & 1) * 64;
  const int fr = lane & 15;
  const int fc = ((((lane >> 4) + ((lane >> 1) & 3)) & 3)) * 8;  // swizzled chunk
  const ushort* rA = As + (wm + fr) * 32 + fc;
  const ushort* rB = Bs + (wn + fr) * 32 + fc;

  f32x4 acc[4][4];
#pragma unroll
  for (int i = 0; i < 4; ++i)
#pragma unroll
    for (int j = 0; j < 4; ++j)
#pragma unroll
      for (int r = 0; r < 4; ++r) acc[i][j][r] = 0.f;

  for (int k0 = 0; k0 < g.K; k0 += 32) {
    G2L(ga0 + k0, lA0);
    G2L(ga1 + k0, lA1);
    G2L(gb0 + k0, lB0);
    G2L(gb1 + k0, lB1);
    __syncthreads();
    short8 af[4], bfr[4];
#pragma unroll
    for (int t = 0; t < 4; ++t) af[t] = *(const short8*)(rA + t * 512);
#pragma unroll
    for (int t = 0; t < 4; ++t) bfr[t] = *(const short8*)(rB + t * 512);
#pragma unroll
    for (int mt = 0; mt < 4; ++mt)
#pragma unroll
      for (int nt = 0; nt < 4; ++nt)
        acc[mt][nt] = __builtin_amdgcn_mfma_f32_16x16x32_bf16(af[mt], bfr[nt], acc[mt][nt], 0, 0, 0);
    __syncthreads();
  }

  // ---- epilogue: C/D map: col = lane&15, row = (lane>>4)*4 + reg  [m89/m91 verified]
  const int cr = (lane >> 4) * 4;
  const int cc = lane & 15;
  ushort* Cu = (ushort*)g.C + (long)z * g.csz;
  float* Cf = (float*)g.C;
#pragma unroll
  for (int mt = 0; mt < 4; ++mt) {
#pragma unroll
    for (int nt = 0; nt < 4; ++nt) {
      const long col = n0 + wn + nt * 16 + cc;
      float bv = 0.f;
      if (MODE == 0 || MODE == 3) bv = g.bias[col];
#pragma unroll
      for (int r = 0; r < 4; ++r) {
        const long row = m0 + wm + mt * 16 + cr + r;
        float v = acc[mt][nt][r] + bv;
        if (MODE == 3) {
          float* dst = (col < 512) ? (Cf + row * 512 + col) : (g.C2 + row * 512 + (col - 512));
          *dst = v;
        } else {
          Cu[row * (long)g.ldc + col] = f2bf(v);
        }
      }
    }
  }
}

// ---------------- converts ----------------
__global__ void cvt_x6(const float* x0, const float* x1, const float* x2,
                       const float* x3, const float* x4, const float* x5, ushort* X) {
  const long m = blockIdx.y;
  const int c4 = (blockIdx.x * 256 + threadIdx.x) * 4;  // 0..3071
  const int p = c4 >> 9, d = c4 & 511;
  const float* xp;
  switch (p) {
    case 0: xp = x0; break; case 1: xp = x1; break; case 2: xp = x2; break;
    case 3: xp = x3; break; case 4: xp = x4; break; default: xp = x5; break;
  }
  float4 v = *(const float4*)(xp + m * 512 + d);
  ushort4 o; o.x = f2bf(v.x); o.y = f2bf(v.y); o.z = f2bf(v.z); o.w = f2bf(v.w);
  *(ushort4*)(X + m * 3072 + c4) = o;
}

__device__ __forceinline__ int chunk_map(int c) { return (c == 0) ? 0 : (c == 1) ? 2 : (c == 2) ? 4 : 5; }

__global__ void cvt_w4(const float* W, ushort* Wq4) {
  const long r = blockIdx.y;                       // 0..2047
  const int c4 = (blockIdx.x * 256 + threadIdx.x) * 4;
  const long wr = (long)chunk_map((int)(r >> 9)) * 512 + (r & 511);
  float4 v = *(const float4*)(W + wr * 3072 + c4);
  ushort4 o; o.x = f2bf(v.x); o.y = f2bf(v.y); o.z = f2bf(v.z); o.w = f2bf(v.w);
  *(ushort4*)(Wq4 + r * 3072 + c4) = o;
}

__global__ void cvt_wout(const float* W, ushort* Wo) {
  const long r = blockIdx.y;
  const int c4 = threadIdx.x * 4;
  float4 v = *(const float4*)(W + r * 1024 + c4);
  ushort4 o; o.x = f2bf(v.x); o.y = f2bf(v.y); o.z = f2bf(v.z); o.w = f2bf(v.w);
  *(ushort4*)(Wo + r * 1024 + c4) = o;
}

__global__ void mk_bias4(const float* bqkv, float* b4) {
  const int n = blockIdx.x * 256 + threadIdx.x;    // 0..2047
  b4[n] = bqkv[chunk_map(n >> 9) * 512 + (n & 511)];
}

// ---------------- V transpose: Vt_b[n][k] = QKV[b*2048+k][1024+n] ----------------
__global__ void transpose_v(const ushort* QKV, ushort* Vt) {
  __shared__ ushort t[64][65];
  const int tid = threadIdx.x;
  const int k0 = blockIdx.x * 64, n0 = blockIdx.y * 64, b = blockIdx.z;
  const ushort* src = QKV + (long)b * 2048 * 2048 + 1024;
#pragma unroll
  for (int i = 0; i < 16; ++i) {
    int idx = i * 256 + tid; int r = idx >> 6, c = idx & 63;
    t[r][c] = src[(long)(k0 + r) * 2048 + (n0 + c)];
  }
  __syncthreads();
  ushort* dst = Vt + (long)b * 1024 * 2048;
#pragma unroll
  for (int i = 0; i < 16; ++i) {
    int idx = i * 256 + tid; int r = idx >> 6, c = idx & 63;
    dst[(long)(n0 + r) * 2048 + (k0 + c)] = t[c][r];
  }
}

// ---------------- softmax (in-place bf16, fused scale + mask) ----------------
__launch_bounds__(256)
__global__ void softmax_rows(ushort* S, const int* mask) {
  const int lane = threadIdx.x & 63;
  const int wave = threadIdx.x >> 6;
  const long row = (long)blockIdx.x * 4 + wave;            // 0..8191
  const int* m = mask + (row >> 11) * 2048;
  ushort* s = S + row * 2048;
  const float scale = 0.04419417382415922f;                // 512^-0.5

  float mx = -INFINITY;
  for (int k = lane; k < 2048; k += 64)
    if (!m[k]) mx = fmaxf(mx, bf2f(s[k]) * scale);
#pragma unroll
  for (int off = 32; off; off >>= 1) mx = fmaxf(mx, __shfl_xor(mx, off));

  float sum = 0.f;
  float loc[32];
  int i = 0;
  for (int k = lane; k < 2048; k += 64, ++i) {
    float e = m[k] ? 0.f : __expf(bf2f(s[k]) * scale - mx);
    loc[i] = e;
    sum += e;
  }
#pragma unroll
  for (int off = 32; off; off >>= 1) sum += __shfl_xor(sum, off);

  float r = 1.f / sum;
  i = 0;
  for (int k = lane; k < 2048; k += 64, ++i) s[k] = f2bf(loc[i] * r);
}

// ---------------- launcher ----------------
extern "C" void kernel_launch(void* const* d_in, const int* in_sizes, int n_in,
                              void* d_out, int out_size, void* d_ws, size_t ws_size,
                              hipStream_t stream) {
  const float* qr = (const float*)d_in[0];
  const float* qi = (const float*)d_in[1];
  const float* kr = (const float*)d_in[2];
  const float* ki = (const float*)d_in[3];
  const float* vr = (const float*)d_in[4];
  const float* vi = (const float*)d_in[5];
  const int* pm = (const int*)d_in[6];
  const float* Wqkv = (const float*)d_in[7];
  const float* bqkv = (const float*)d_in[8];
  const float* Wout = (const float*)d_in[9];
  const float* bout = (const float*)d_in[10];
  float* out = (float*)d_out;

  // ws layout (bytes):
  char* base = (char*)d_ws;
  ushort* QKV   = (ushort*)(base);                         // 8192x2048 bf16   33,554,432
  ushort* Wq4   = (ushort*)(base + 33554432);              // 2048x3072 bf16   12,582,912
  ushort* Wo    = (ushort*)(base + 46137344);              // 1024x1024 bf16    2,097,152
  float*  b4    = (float*) (base + 48234496);              // 2048 fp32             8,192
  char*   uni   = base + 48242688;
  ushort* Xbf   = (ushort*)(uni);                          // 8192x3072 bf16   50,331,648 (dies after stage1)
  ushort* Vt    = (ushort*)(uni);                          // 4x1024x2048 bf16 16,777,216
  ushort* S     = (ushort*)(uni + 16777216);               // 4x2048x2048 bf16 33,554,432
  ushort* AO    = (ushort*)(uni + 50331648);               // 8192x1024 bf16   16,777,216
  // total 115,351,552 bytes

  // converts
  cvt_x6<<<dim3(3, 8192), 256, 0, stream>>>(qr, qi, kr, ki, vr, vi, Xbf);
  cvt_w4<<<dim3(3, 2048), 256, 0, stream>>>(Wqkv, Wq4);
  cvt_wout<<<dim3(1, 1024), 256, 0, stream>>>(Wout, Wo);
  mk_bias4<<<8, 256, 0, stream>>>(bqkv, b4);

  // stage 1: QKV = Xbf(8192x3072) . Wq4(2048x3072)^T + b4  -> bf16
  {
    MArgs a{};
    a.A = Xbf; a.lda = 3072; a.asz = 0;
    a.B = Wq4; a.ldb = 3072; a.bsz = 0;
    a.C = QKV; a.ldc = 2048; a.csz = 0;
    a.K = 3072; a.bias = b4;
    mfma_gemm<0><<<dim3(16, 64, 1), 256, 0, stream>>>(a);
  }

  // V transpose (reads QKV cols 1024..2047)
  transpose_v<<<dim3(32, 16, 4), 256, 0, stream>>>(QKV, Vt);

  // stage 2: S_b = Q_b(2048x512) . K_b(2048x512)^T  -> bf16 (raw scores)
  {
    MArgs a{};
    a.A = QKV;        a.lda = 2048; a.asz = (long)2048 * 2048;
    a.B = QKV + 512;  a.ldb = 2048; a.bsz = (long)2048 * 2048;
    a.C = S;          a.ldc = 2048; a.csz = (long)2048 * 2048;
    a.K = 512;
    mfma_gemm<1><<<dim3(16, 16, 4), 256, 0, stream>>>(a);
  }

  // stage 3: softmax rows in place (scale + mask + exp + norm)
  softmax_rows<<<2048, 256, 0, stream>>>(S, pm);

  // stage 4: AO_b = P_b(2048x2048) . Vt_b(1024x2048)^T  -> bf16
  {
    MArgs a{};
    a.A = S;  a.lda = 2048; a.asz = (long)2048 * 2048;
    a.B = Vt; a.ldb = 2048; a.bsz = (long)1024 * 2048;
    a.C = AO; a.ldc = 1024; a.csz = (long)2048 * 1024;
    a.K = 2048;
    mfma_gemm<2><<<dim3(8, 16, 4), 256, 0, stream>>>(a);
  }

  // stage 5: out = AO(8192x1024) . Wo(1024x1024)^T + bout -> fp32 split
  {
    MArgs a{};
    a.A = AO; a.lda = 1024; a.asz = 0;
    a.B = Wo; a.ldb = 1024; a.bsz = 0;
    a.C = out; a.ldc = 512; a.csz = 0;
    a.C2 = out + (long)8192 * 512;
    a.K = 1024; a.bias = bout;
    mfma_gemm<3><<<dim3(8, 64, 1), 256, 0, stream>>>(a);
  }
}

// Round 4
// 464.594 us; speedup vs baseline: 6.4530x; 1.1142x over previous
//
#include <hip/hip_runtime.h>
#include <cstdint>
#include <cstddef>

typedef unsigned short ushort;
typedef __attribute__((ext_vector_type(8))) short short8;    // 8 x bf16 (4 VGPRs)
typedef __attribute__((ext_vector_type(16))) float f32x16;   // 32x32 accumulator

__device__ __forceinline__ float bf2f(ushort u) {
  union { unsigned u; float f; } c; c.u = ((unsigned)u) << 16; return c.f;
}
__device__ __forceinline__ ushort f2bf(float f) {
  union { float f; unsigned u; } c; c.f = f;
  unsigned u = c.u;
  return (ushort)((u + 0x7fffu + ((u >> 16) & 1u)) >> 16);   // RNE
}

#define G2L(g, l) __builtin_amdgcn_global_load_lds( \
    (const __attribute__((address_space(1))) void*)(g), \
    (__attribute__((address_space(3))) void*)(l), 16, 0, 0)

// ---------------- MFMA GEMM: C[M,N] = A[M,K] . B[N,K]^T (+bias) ----------------
// 128x128 tile, BK=32, 4 waves, each wave 64x64 via 2x2 MFMA 32x32x16 tiles.
// LDS layout: [row 0..127][k 0..31] with chunk swizzle: global 8-elem chunk g of
// row r lives at LDS chunk (g + (r>>1))&3.  (zero bank conflicts, verified R3)
// MODE 0: stage1 qkv  (bias4 fp32, write bf16)
// MODE 1: stage2 scores / MODE 2: stage4 PV (no bias, write bf16)
// MODE 3: stage5 out  (bias fp32, write fp32 split at col 512)
struct MArgs {
  const ushort* A; int lda; long asz;
  const ushort* B; int ldb; long bsz;
  void* C; int ldc; long csz;
  int K;
  const float* bias;
  float* C2;
};

template<int MODE>
__launch_bounds__(256)
__global__ void mfma_gemm(MArgs g) {
  __shared__ ushort As[128 * 32];
  __shared__ ushort Bs[128 * 32];
  const int tid = threadIdx.x;
  const int lane = tid & 63;
  const int wave = tid >> 6;
  const int z = blockIdx.z;
  const long m0 = (long)blockIdx.y * 128;
  const long n0 = (long)blockIdx.x * 128;
  const ushort* A = g.A + (long)z * g.asz;
  const ushort* B = g.B + (long)z * g.bsz;

  // ---- staging addresses (fixed per lane; swizzle on the global k-offset)
  const int srow = lane >> 2;                                  // row within 16-row block
  const int skq = (((lane & 3) - ((lane >> 3) & 3)) & 3) * 8;  // swizzled global k-offset
  const ushort* ga0 = A + (m0 + wave * 16 + srow) * g.lda + skq;
  const ushort* ga1 = A + (m0 + (wave + 4) * 16 + srow) * g.lda + skq;
  const ushort* gb0 = B + (n0 + wave * 16 + srow) * g.ldb + skq;
  const ushort* gb1 = B + (n0 + (wave + 4) * 16 + srow) * g.ldb + skq;
  ushort* lA0 = As + tid * 8;
  ushort* lA1 = As + 2048 + tid * 8;
  ushort* lB0 = Bs + tid * 8;
  ushort* lB1 = Bs + 2048 + tid * 8;

  // ---- fragment read addresses
  // A operand 32x32x16: lane holds A[m=lane&31][k = 8*(lane>>5) + j], j=0..7
  // swizzled LDS chunk for (q = kchunk, row): (q + (row>>1))&3
  const int wm = (wave >> 1) * 64;
  const int wn = (wave & 1) * 64;
  const int fr = lane & 31;
  const int c0 = ((((lane >> 5) + ((lane >> 1) & 3))) & 3) * 8;  // k-half 0 chunk offset
  const int c1 = c0 ^ 16;                                        // k-half 1: chunk+2 mod 4
  const ushort* rA = As + (wm + fr) * 32;
  const ushort* rB = Bs + (wn + fr) * 32;

  f32x16 acc[2][2];
#pragma unroll
  for (int i = 0; i < 2; ++i)
#pragma unroll
    for (int j = 0; j < 2; ++j)
#pragma unroll
      for (int r = 0; r < 16; ++r) acc[i][j][r] = 0.f;

  for (int k0 = 0; k0 < g.K; k0 += 32) {
    G2L(ga0 + k0, lA0);
    G2L(ga1 + k0, lA1);
    G2L(gb0 + k0, lB0);
    G2L(gb1 + k0, lB1);
    __syncthreads();
    short8 af[2][2], bf[2][2];   // [mt/nt][khalf]
#pragma unroll
    for (int mt = 0; mt < 2; ++mt) {
      af[mt][0] = *(const short8*)(rA + mt * 1024 + c0);
      af[mt][1] = *(const short8*)(rA + mt * 1024 + c1);
      bf[mt][0] = *(const short8*)(rB + mt * 1024 + c0);
      bf[mt][1] = *(const short8*)(rB + mt * 1024 + c1);
    }
#pragma unroll
    for (int h = 0; h < 2; ++h)
#pragma unroll
      for (int mt = 0; mt < 2; ++mt)
#pragma unroll
        for (int nt = 0; nt < 2; ++nt)
          acc[mt][nt] = __builtin_amdgcn_mfma_f32_32x32x16_bf16(af[mt][h], bf[nt][h], acc[mt][nt], 0, 0, 0);
    __syncthreads();
  }

  // ---- epilogue: C/D map (m74/m101): col=lane&31, row=(reg&3)+8*(reg>>2)+4*(lane>>5)
  const int cc = lane & 31;
  const int rbase = 4 * (lane >> 5);
  ushort* Cu = (ushort*)g.C + (long)z * g.csz;
  float* Cf = (float*)g.C;
#pragma unroll
  for (int mt = 0; mt < 2; ++mt) {
#pragma unroll
    for (int nt = 0; nt < 2; ++nt) {
      const long col = n0 + wn + nt * 32 + cc;
      float bv = 0.f;
      if (MODE == 0 || MODE == 3) bv = g.bias[col];
#pragma unroll
      for (int r = 0; r < 16; ++r) {
        const long row = m0 + wm + mt * 32 + (r & 3) + 8 * (r >> 2) + rbase;
        float v = acc[mt][nt][r] + bv;
        if (MODE == 3) {
          float* dst = (col < 512) ? (Cf + row * 512 + col) : (g.C2 + row * 512 + (col - 512));
          *dst = v;
        } else {
          Cu[row * (long)g.ldc + col] = f2bf(v);
        }
      }
    }
  }
}

// ---------------- converts ----------------
__global__ void cvt_x6(const float* x0, const float* x1, const float* x2,
                       const float* x3, const float* x4, const float* x5, ushort* X) {
  const long m = blockIdx.y;
  const int c4 = (blockIdx.x * 256 + threadIdx.x) * 4;  // 0..3071
  const int p = c4 >> 9, d = c4 & 511;
  const float* xp;
  switch (p) {
    case 0: xp = x0; break; case 1: xp = x1; break; case 2: xp = x2; break;
    case 3: xp = x3; break; case 4: xp = x4; break; default: xp = x5; break;
  }
  float4 v = *(const float4*)(xp + m * 512 + d);
  ushort4 o; o.x = f2bf(v.x); o.y = f2bf(v.y); o.z = f2bf(v.z); o.w = f2bf(v.w);
  *(ushort4*)(X + m * 3072 + c4) = o;
}

__device__ __forceinline__ int chunk_map(int c) { return (c == 0) ? 0 : (c == 1) ? 2 : (c == 2) ? 4 : 5; }

__global__ void cvt_w4(const float* W, ushort* Wq4) {
  const long r = blockIdx.y;                       // 0..2047
  const int c4 = (blockIdx.x * 256 + threadIdx.x) * 4;
  const long wr = (long)chunk_map((int)(r >> 9)) * 512 + (r & 511);
  float4 v = *(const float4*)(W + wr * 3072 + c4);
  ushort4 o; o.x = f2bf(v.x); o.y = f2bf(v.y); o.z = f2bf(v.z); o.w = f2bf(v.w);
  *(ushort4*)(Wq4 + r * 3072 + c4) = o;
}

__global__ void cvt_wout(const float* W, ushort* Wo) {
  const long r = blockIdx.y;
  const int c4 = threadIdx.x * 4;
  float4 v = *(const float4*)(W + r * 1024 + c4);
  ushort4 o; o.x = f2bf(v.x); o.y = f2bf(v.y); o.z = f2bf(v.z); o.w = f2bf(v.w);
  *(ushort4*)(Wo + r * 1024 + c4) = o;
}

__global__ void mk_bias4(const float* bqkv, float* b4) {
  const int n = blockIdx.x * 256 + threadIdx.x;    // 0..2047
  b4[n] = bqkv[chunk_map(n >> 9) * 512 + (n & 511)];
}

// ---------------- V transpose: Vt_b[n][k] = QKV[b*2048+k][1024+n] ----------------
__global__ void transpose_v(const ushort* QKV, ushort* Vt) {
  __shared__ ushort t[64][65];
  const int tid = threadIdx.x;
  const int k0 = blockIdx.x * 64, n0 = blockIdx.y * 64, b = blockIdx.z;
  const ushort* src = QKV + (long)b * 2048 * 2048 + 1024;
#pragma unroll
  for (int i = 0; i < 16; ++i) {
    int idx = i * 256 + tid; int r = idx >> 6, c = idx & 63;
    t[r][c] = src[(long)(k0 + r) * 2048 + (n0 + c)];
  }
  __syncthreads();
  ushort* dst = Vt + (long)b * 1024 * 2048;
#pragma unroll
  for (int i = 0; i < 16; ++i) {
    int idx = i * 256 + tid; int r = idx >> 6, c = idx & 63;
    dst[(long)(n0 + r) * 2048 + (k0 + c)] = t[c][r];
  }
}

// ---------------- softmax: lane owns one contiguous 64B chunk (32 elems) ----------------
__launch_bounds__(256)
__global__ void softmax_rows(ushort* S, const int* mask) {
  const int lane = threadIdx.x & 63;
  const int wave = threadIdx.x >> 6;
  const long row = (long)blockIdx.x * 4 + wave;            // 0..8191
  const int* m = mask + (row >> 11) * 2048 + lane * 32;
  ushort* s = S + row * 2048 + lane * 32;
  const float scale = 0.04419417382415922f;                // 512^-0.5

  short8 raw[4];
#pragma unroll
  for (int i = 0; i < 4; ++i) raw[i] = *(const short8*)(s + i * 8);
  int4 mi[8];
#pragma unroll
  for (int i = 0; i < 8; ++i) mi[i] = *(const int4*)(m + i * 4);

  float v[32];
  int mk[32];
#pragma unroll
  for (int i = 0; i < 8; ++i) {
    mk[i * 4 + 0] = mi[i].x; mk[i * 4 + 1] = mi[i].y;
    mk[i * 4 + 2] = mi[i].z; mk[i * 4 + 3] = mi[i].w;
  }
#pragma unroll
  for (int i = 0; i < 32; ++i) v[i] = bf2f((ushort)raw[i >> 3][i & 7]) * scale;

  float mx = -INFINITY;
#pragma unroll
  for (int i = 0; i < 32; ++i) if (!mk[i]) mx = fmaxf(mx, v[i]);
#pragma unroll
  for (int off = 32; off; off >>= 1) mx = fmaxf(mx, __shfl_xor(mx, off));

  float sum = 0.f;
#pragma unroll
  for (int i = 0; i < 32; ++i) {
    float e = mk[i] ? 0.f : __expf(v[i] - mx);
    v[i] = e;
    sum += e;
  }
#pragma unroll
  for (int off = 32; off; off >>= 1) sum += __shfl_xor(sum, off);

  float r = 1.f / sum;
  short8 out[4];
#pragma unroll
  for (int i = 0; i < 32; ++i) out[i >> 3][i & 7] = (short)f2bf(v[i] * r);
#pragma unroll
  for (int i = 0; i < 4; ++i) *(short8*)(s + i * 8) = out[i];
}

// ---------------- launcher ----------------
extern "C" void kernel_launch(void* const* d_in, const int* in_sizes, int n_in,
                              void* d_out, int out_size, void* d_ws, size_t ws_size,
                              hipStream_t stream) {
  const float* qr = (const float*)d_in[0];
  const float* qi = (const float*)d_in[1];
  const float* kr = (const float*)d_in[2];
  const float* ki = (const float*)d_in[3];
  const float* vr = (const float*)d_in[4];
  const float* vi = (const float*)d_in[5];
  const int* pm = (const int*)d_in[6];
  const float* Wqkv = (const float*)d_in[7];
  const float* bqkv = (const float*)d_in[8];
  const float* Wout = (const float*)d_in[9];
  const float* bout = (const float*)d_in[10];
  float* out = (float*)d_out;

  // ws layout (bytes):
  char* base = (char*)d_ws;
  ushort* QKV   = (ushort*)(base);                         // 8192x2048 bf16   33,554,432
  ushort* Wq4   = (ushort*)(base + 33554432);              // 2048x3072 bf16   12,582,912
  ushort* Wo    = (ushort*)(base + 46137344);              // 1024x1024 bf16    2,097,152
  float*  b4    = (float*) (base + 48234496);              // 2048 fp32             8,192
  char*   uni   = base + 48242688;
  ushort* Xbf   = (ushort*)(uni);                          // 8192x3072 bf16   50,331,648 (dies after stage1)
  ushort* Vt    = (ushort*)(uni);                          // 4x1024x2048 bf16 16,777,216
  ushort* S     = (ushort*)(uni + 16777216);               // 4x2048x2048 bf16 33,554,432
  ushort* AO    = (ushort*)(uni + 50331648);               // 8192x1024 bf16   16,777,216
  // total 115,351,552 bytes

  // converts
  cvt_x6<<<dim3(3, 8192), 256, 0, stream>>>(qr, qi, kr, ki, vr, vi, Xbf);
  cvt_w4<<<dim3(3, 2048), 256, 0, stream>>>(Wqkv, Wq4);
  cvt_wout<<<dim3(1, 1024), 256, 0, stream>>>(Wout, Wo);
  mk_bias4<<<8, 256, 0, stream>>>(bqkv, b4);

  // stage 1: QKV = Xbf(8192x3072) . Wq4(2048x3072)^T + b4  -> bf16
  {
    MArgs a{};
    a.A = Xbf; a.lda = 3072; a.asz = 0;
    a.B = Wq4; a.ldb = 3072; a.bsz = 0;
    a.C = QKV; a.ldc = 2048; a.csz = 0;
    a.K = 3072; a.bias = b4;
    mfma_gemm<0><<<dim3(16, 64, 1), 256, 0, stream>>>(a);
  }

  // V transpose (reads QKV cols 1024..2047)
  transpose_v<<<dim3(32, 16, 4), 256, 0, stream>>>(QKV, Vt);

  // stage 2: S_b = Q_b(2048x512) . K_b(2048x512)^T  -> bf16 (raw scores)
  {
    MArgs a{};
    a.A = QKV;        a.lda = 2048; a.asz = (long)2048 * 2048;
    a.B = QKV + 512;  a.ldb = 2048; a.bsz = (long)2048 * 2048;
    a.C = S;          a.ldc = 2048; a.csz = (long)2048 * 2048;
    a.K = 512;
    mfma_gemm<1><<<dim3(16, 16, 4), 256, 0, stream>>>(a);
  }

  // stage 3: softmax rows in place (scale + mask + exp + norm)
  softmax_rows<<<2048, 256, 0, stream>>>(S, pm);

  // stage 4: AO_b = P_b(2048x2048) . Vt_b(1024x2048)^T  -> bf16
  {
    MArgs a{};
    a.A = S;  a.lda = 2048; a.asz = (long)2048 * 2048;
    a.B = Vt; a.ldb = 2048; a.bsz = (long)1024 * 2048;
    a.C = AO; a.ldc = 1024; a.csz = (long)2048 * 1024;
    a.K = 2048;
    mfma_gemm<2><<<dim3(8, 16, 4), 256, 0, stream>>>(a);
  }

  // stage 5: out = AO(8192x1024) . Wo(1024x1024)^T + bout -> fp32 split
  {
    MArgs a{};
    a.A = AO; a.lda = 1024; a.asz = 0;
    a.B = Wo; a.ldb = 1024; a.bsz = 0;
    a.C = out; a.ldc = 512; a.csz = 0;
    a.C2 = out + (long)8192 * 512;
    a.K = 1024; a.bias = bout;
    mfma_gemm<3><<<dim3(8, 64, 1), 256, 0, stream>>>(a);
  }
}

// Round 5
// 422.091 us; speedup vs baseline: 7.1028x; 1.1007x over previous
//
#include <hip/hip_runtime.h>
#include <cstdint>
#include <cstddef>

typedef unsigned short ushort;
typedef __attribute__((ext_vector_type(8))) short short8;    // 8 x bf16 (4 VGPRs)
typedef __attribute__((ext_vector_type(16))) float f32x16;   // 32x32 accumulator

__device__ __forceinline__ float bf2f(ushort u) {
  union { unsigned u; float f; } c; c.u = ((unsigned)u) << 16; return c.f;
}
__device__ __forceinline__ ushort f2bf(float f) {
  union { float f; unsigned u; } c; c.f = f;
  unsigned u = c.u;
  return (ushort)((u + 0x7fffu + ((u >> 16) & 1u)) >> 16);   // RNE
}

#define G2L(g, l) __builtin_amdgcn_global_load_lds( \
    (const __attribute__((address_space(1))) void*)(g), \
    (__attribute__((address_space(3))) void*)(l), 16, 0, 0)

// ---------------- MFMA GEMM: C[M,N] = A[M,K] . B[N,K]^T (+bias) ----------------
// 128x128 tile, BK=64, 4 waves, each wave 64x64 via 2x2 MFMA 32x32x16 tiles,
// 32 MFMA per barrier pair (vs 16 in R4) to amortize the vmcnt(0) drain.
// LDS layout: [row 0..127][k-chunk 0..7] (chunk = 8 elems = 16B), row stride 128B.
// Swizzle: global chunk q of row r lives at LDS chunk (q + r) & 7.
//   -> fragment-read bank group = ((l>>5) + 2h + (l&7)) & 7: all 8 distinct per
//      8-lane phase => conflict-free.  Staging is a within-row permutation.
// MODE 0: stage1 qkv  (bias4 fp32, write bf16)
// MODE 1: stage2 scores / MODE 2: stage4 PV (no bias, write bf16)
// MODE 3: stage5 out  (bias fp32, write fp32 split at col 512)
struct MArgs {
  const ushort* A; int lda; long asz;
  const ushort* B; int ldb; long bsz;
  void* C; int ldc; long csz;
  int K;
  const float* bias;
  float* C2;
};

template<int MODE>
__launch_bounds__(256)
__global__ void mfma_gemm(MArgs g) {
  __shared__ ushort As[128 * 64];
  __shared__ ushort Bs[128 * 64];
  const int tid = threadIdx.x;
  const int lane = tid & 63;
  const int wave = tid >> 6;
  const int z = blockIdx.z;
  const long m0 = (long)blockIdx.y * 128;
  const long n0 = (long)blockIdx.x * 128;
  const ushort* A = g.A + (long)z * g.asz;
  const ushort* B = g.B + (long)z * g.bsz;

  // ---- staging: group gp covers rows gp*32..gp*32+31; thread -> row tid>>3, LDS chunk tid&7
  // global chunk q = (ldschunk - row) & 7
  const int srow = tid >> 3;                       // row within 32-row group? no: within 128 via gp*32+
  const int sk = ((((tid & 7) - (srow & 7)) & 7)) * 8;  // swizzled global k-offset (elems)
  const ushort* ga[4]; const ushort* gb[4];
  ushort* la[4]; ushort* lb[4];
#pragma unroll
  for (int gp = 0; gp < 4; ++gp) {
    ga[gp] = A + (m0 + gp * 32 + srow) * g.lda + sk;
    gb[gp] = B + (n0 + gp * 32 + srow) * g.ldb + sk;
    la[gp] = As + gp * 2048 + tid * 8;
    lb[gp] = Bs + gp * 2048 + tid * 8;
  }

  // ---- fragment read addresses
  // lane l needs A[m = l&31][k = 16h + 8*(l>>5) + j]; LDS chunk = (2h + (l>>5) + (l&7)) & 7
  const int wm = (wave >> 1) * 64;
  const int wn = (wave & 1) * 64;
  const int fr = lane & 31;
  const ushort* rA = As + (wm + fr) * 64;
  const ushort* rB = Bs + (wn + fr) * 64;
  const int cbase = ((lane >> 5) + (lane & 7)) & 7;
  int offk[4];
#pragma unroll
  for (int h = 0; h < 4; ++h) offk[h] = ((cbase + 2 * h) & 7) * 8;

  f32x16 acc[2][2];
#pragma unroll
  for (int i = 0; i < 2; ++i)
#pragma unroll
    for (int j = 0; j < 2; ++j)
#pragma unroll
      for (int r = 0; r < 16; ++r) acc[i][j][r] = 0.f;

  for (int k0 = 0; k0 < g.K; k0 += 64) {
#pragma unroll
    for (int gp = 0; gp < 4; ++gp) G2L(ga[gp] + k0, la[gp]);
#pragma unroll
    for (int gp = 0; gp < 4; ++gp) G2L(gb[gp] + k0, lb[gp]);
    __syncthreads();
#pragma unroll
    for (int h = 0; h < 4; ++h) {
      short8 a0 = *(const short8*)(rA + offk[h]);
      short8 a1 = *(const short8*)(rA + 2048 + offk[h]);
      short8 b0 = *(const short8*)(rB + offk[h]);
      short8 b1 = *(const short8*)(rB + 2048 + offk[h]);
      acc[0][0] = __builtin_amdgcn_mfma_f32_32x32x16_bf16(a0, b0, acc[0][0], 0, 0, 0);
      acc[0][1] = __builtin_amdgcn_mfma_f32_32x32x16_bf16(a0, b1, acc[0][1], 0, 0, 0);
      acc[1][0] = __builtin_amdgcn_mfma_f32_32x32x16_bf16(a1, b0, acc[1][0], 0, 0, 0);
      acc[1][1] = __builtin_amdgcn_mfma_f32_32x32x16_bf16(a1, b1, acc[1][1], 0, 0, 0);
    }
    __syncthreads();
  }

  // ---- epilogue: C/D map (m74/m101): col=lane&31, row=(reg&3)+8*(reg>>2)+4*(lane>>5)
  const int cc = lane & 31;
  const int rbase = 4 * (lane >> 5);
  ushort* Cu = (ushort*)g.C + (long)z * g.csz;
  float* Cf = (float*)g.C;
#pragma unroll
  for (int mt = 0; mt < 2; ++mt) {
#pragma unroll
    for (int nt = 0; nt < 2; ++nt) {
      const long col = n0 + wn + nt * 32 + cc;
      float bv = 0.f;
      if (MODE == 0 || MODE == 3) bv = g.bias[col];
#pragma unroll
      for (int r = 0; r < 16; ++r) {
        const long row = m0 + wm + mt * 32 + (r & 3) + 8 * (r >> 2) + rbase;
        float v = acc[mt][nt][r] + bv;
        if (MODE == 3) {
          float* dst = (col < 512) ? (Cf + row * 512 + col) : (g.C2 + row * 512 + (col - 512));
          *dst = v;
        } else {
          Cu[row * (long)g.ldc + col] = f2bf(v);
        }
      }
    }
  }
}

// ---------------- converts ----------------
__global__ void cvt_x6(const float* x0, const float* x1, const float* x2,
                       const float* x3, const float* x4, const float* x5, ushort* X) {
  const long m = blockIdx.y;
  const int c4 = (blockIdx.x * 256 + threadIdx.x) * 4;  // 0..3071
  const int p = c4 >> 9, d = c4 & 511;
  const float* xp;
  switch (p) {
    case 0: xp = x0; break; case 1: xp = x1; break; case 2: xp = x2; break;
    case 3: xp = x3; break; case 4: xp = x4; break; default: xp = x5; break;
  }
  float4 v = *(const float4*)(xp + m * 512 + d);
  ushort4 o; o.x = f2bf(v.x); o.y = f2bf(v.y); o.z = f2bf(v.z); o.w = f2bf(v.w);
  *(ushort4*)(X + m * 3072 + c4) = o;
}

__device__ __forceinline__ int chunk_map(int c) { return (c == 0) ? 0 : (c == 1) ? 2 : (c == 2) ? 4 : 5; }

__global__ void cvt_w4(const float* W, ushort* Wq4) {
  const long r = blockIdx.y;                       // 0..2047
  const int c4 = (blockIdx.x * 256 + threadIdx.x) * 4;
  const long wr = (long)chunk_map((int)(r >> 9)) * 512 + (r & 511);
  float4 v = *(const float4*)(W + wr * 3072 + c4);
  ushort4 o; o.x = f2bf(v.x); o.y = f2bf(v.y); o.z = f2bf(v.z); o.w = f2bf(v.w);
  *(ushort4*)(Wq4 + r * 3072 + c4) = o;
}

__global__ void cvt_wout(const float* W, ushort* Wo) {
  const long r = blockIdx.y;
  const int c4 = threadIdx.x * 4;
  float4 v = *(const float4*)(W + r * 1024 + c4);
  ushort4 o; o.x = f2bf(v.x); o.y = f2bf(v.y); o.z = f2bf(v.z); o.w = f2bf(v.w);
  *(ushort4*)(Wo + r * 1024 + c4) = o;
}

__global__ void mk_bias4(const float* bqkv, float* b4) {
  const int n = blockIdx.x * 256 + threadIdx.x;    // 0..2047
  b4[n] = bqkv[chunk_map(n >> 9) * 512 + (n & 511)];
}

// ---------------- V transpose: Vt_b[n][k] = QKV[b*2048+k][1024+n] ----------------
__global__ void transpose_v(const ushort* QKV, ushort* Vt) {
  __shared__ ushort t[64][65];
  const int tid = threadIdx.x;
  const int k0 = blockIdx.x * 64, n0 = blockIdx.y * 64, b = blockIdx.z;
  const ushort* src = QKV + (long)b * 2048 * 2048 + 1024;
#pragma unroll
  for (int i = 0; i < 16; ++i) {
    int idx = i * 256 + tid; int r = idx >> 6, c = idx & 63;
    t[r][c] = src[(long)(k0 + r) * 2048 + (n0 + c)];
  }
  __syncthreads();
  ushort* dst = Vt + (long)b * 1024 * 2048;
#pragma unroll
  for (int i = 0; i < 16; ++i) {
    int idx = i * 256 + tid; int r = idx >> 6, c = idx & 63;
    dst[(long)(n0 + r) * 2048 + (k0 + c)] = t[c][r];
  }
}

// ---------------- softmax: lane owns one contiguous 64B chunk (32 elems) ----------------
__launch_bounds__(256)
__global__ void softmax_rows(ushort* S, const int* mask) {
  const int lane = threadIdx.x & 63;
  const int wave = threadIdx.x >> 6;
  const long row = (long)blockIdx.x * 4 + wave;            // 0..8191
  const int* m = mask + (row >> 11) * 2048 + lane * 32;
  ushort* s = S + row * 2048 + lane * 32;
  const float scale = 0.04419417382415922f;                // 512^-0.5

  short8 raw[4];
#pragma unroll
  for (int i = 0; i < 4; ++i) raw[i] = *(const short8*)(s + i * 8);
  int4 mi[8];
#pragma unroll
  for (int i = 0; i < 8; ++i) mi[i] = *(const int4*)(m + i * 4);

  float v[32];
  int mk[32];
#pragma unroll
  for (int i = 0; i < 8; ++i) {
    mk[i * 4 + 0] = mi[i].x; mk[i * 4 + 1] = mi[i].y;
    mk[i * 4 + 2] = mi[i].z; mk[i * 4 + 3] = mi[i].w;
  }
#pragma unroll
  for (int i = 0; i < 32; ++i) v[i] = bf2f((ushort)raw[i >> 3][i & 7]) * scale;

  float mx = -INFINITY;
#pragma unroll
  for (int i = 0; i < 32; ++i) if (!mk[i]) mx = fmaxf(mx, v[i]);
#pragma unroll
  for (int off = 32; off; off >>= 1) mx = fmaxf(mx, __shfl_xor(mx, off));

  float sum = 0.f;
#pragma unroll
  for (int i = 0; i < 32; ++i) {
    float e = mk[i] ? 0.f : __expf(v[i] - mx);
    v[i] = e;
    sum += e;
  }
#pragma unroll
  for (int off = 32; off; off >>= 1) sum += __shfl_xor(sum, off);

  float r = 1.f / sum;
  short8 out[4];
#pragma unroll
  for (int i = 0; i < 32; ++i) out[i >> 3][i & 7] = (short)f2bf(v[i] * r);
#pragma unroll
  for (int i = 0; i < 4; ++i) *(short8*)(s + i * 8) = out[i];
}

// ---------------- launcher ----------------
extern "C" void kernel_launch(void* const* d_in, const int* in_sizes, int n_in,
                              void* d_out, int out_size, void* d_ws, size_t ws_size,
                              hipStream_t stream) {
  const float* qr = (const float*)d_in[0];
  const float* qi = (const float*)d_in[1];
  const float* kr = (const float*)d_in[2];
  const float* ki = (const float*)d_in[3];
  const float* vr = (const float*)d_in[4];
  const float* vi = (const float*)d_in[5];
  const int* pm = (const int*)d_in[6];
  const float* Wqkv = (const float*)d_in[7];
  const float* bqkv = (const float*)d_in[8];
  const float* Wout = (const float*)d_in[9];
  const float* bout = (const float*)d_in[10];
  float* out = (float*)d_out;

  // ws layout (bytes):
  char* base = (char*)d_ws;
  ushort* QKV   = (ushort*)(base);                         // 8192x2048 bf16   33,554,432
  ushort* Wq4   = (ushort*)(base + 33554432);              // 2048x3072 bf16   12,582,912
  ushort* Wo    = (ushort*)(base + 46137344);              // 1024x1024 bf16    2,097,152
  float*  b4    = (float*) (base + 48234496);              // 2048 fp32             8,192
  char*   uni   = base + 48242688;
  ushort* Xbf   = (ushort*)(uni);                          // 8192x3072 bf16   50,331,648 (dies after stage1)
  ushort* Vt    = (ushort*)(uni);                          // 4x1024x2048 bf16 16,777,216
  ushort* S     = (ushort*)(uni + 16777216);               // 4x2048x2048 bf16 33,554,432
  ushort* AO    = (ushort*)(uni + 50331648);               // 8192x1024 bf16   16,777,216
  // total 115,351,552 bytes

  // converts
  cvt_x6<<<dim3(3, 8192), 256, 0, stream>>>(qr, qi, kr, ki, vr, vi, Xbf);
  cvt_w4<<<dim3(3, 2048), 256, 0, stream>>>(Wqkv, Wq4);
  cvt_wout<<<dim3(1, 1024), 256, 0, stream>>>(Wout, Wo);
  mk_bias4<<<8, 256, 0, stream>>>(bqkv, b4);

  // stage 1: QKV = Xbf(8192x3072) . Wq4(2048x3072)^T + b4  -> bf16
  {
    MArgs a{};
    a.A = Xbf; a.lda = 3072; a.asz = 0;
    a.B = Wq4; a.ldb = 3072; a.bsz = 0;
    a.C = QKV; a.ldc = 2048; a.csz = 0;
    a.K = 3072; a.bias = b4;
    mfma_gemm<0><<<dim3(16, 64, 1), 256, 0, stream>>>(a);
  }

  // V transpose (reads QKV cols 1024..2047)
  transpose_v<<<dim3(32, 16, 4), 256, 0, stream>>>(QKV, Vt);

  // stage 2: S_b = Q_b(2048x512) . K_b(2048x512)^T  -> bf16 (raw scores)
  {
    MArgs a{};
    a.A = QKV;        a.lda = 2048; a.asz = (long)2048 * 2048;
    a.B = QKV + 512;  a.ldb = 2048; a.bsz = (long)2048 * 2048;
    a.C = S;          a.ldc = 2048; a.csz = (long)2048 * 2048;
    a.K = 512;
    mfma_gemm<1><<<dim3(16, 16, 4), 256, 0, stream>>>(a);
  }

  // stage 3: softmax rows in place (scale + mask + exp + norm)
  softmax_rows<<<2048, 256, 0, stream>>>(S, pm);

  // stage 4: AO_b = P_b(2048x2048) . Vt_b(1024x2048)^T  -> bf16
  {
    MArgs a{};
    a.A = S;  a.lda = 2048; a.asz = (long)2048 * 2048;
    a.B = Vt; a.ldb = 2048; a.bsz = (long)1024 * 2048;
    a.C = AO; a.ldc = 1024; a.csz = (long)2048 * 1024;
    a.K = 2048;
    mfma_gemm<2><<<dim3(8, 16, 4), 256, 0, stream>>>(a);
  }

  // stage 5: out = AO(8192x1024) . Wo(1024x1024)^T + bout -> fp32 split
  {
    MArgs a{};
    a.A = AO; a.lda = 1024; a.asz = 0;
    a.B = Wo; a.ldb = 1024; a.bsz = 0;
    a.C = out; a.ldc = 512; a.csz = 0;
    a.C2 = out + (long)8192 * 512;
    a.K = 1024; a.bias = bout;
    mfma_gemm<3><<<dim3(8, 64, 1), 256, 0, stream>>>(a);
  }
}